// Round 5
// baseline (277.406 us; speedup 1.0000x reference)
//
#include <hip/hip_runtime.h>
#include <math.h>
#include <stdint.h>

#define DD 32
// group record: 56 u32 words (224B): words[0..7]=s[16] bf16, words[8..55]=me[3][32] bf16
// item  record: 24 u32 words (96B):  words[0..7]=t[16] bf16, words[8..23]=ie[32] bf16
#define GRECW 56
#define IRECW 24

__device__ __forceinline__ uint32_t bf16rne(float f) {
    uint32_t u = __float_as_uint(f);
    return (u + 0x7fffu + ((u >> 16) & 1u)) >> 16;
}
__device__ __forceinline__ uint32_t pack2(float a, float b) {
    return bf16rne(a) | (bf16rne(b) << 16);
}
#define BLO(u) __uint_as_float((u) << 16)
#define BHI(u) __uint_as_float((u) & 0xffff0000u)

// pick s[4q..4q+3] with static indexing per branch (rule #20: no runtime array idx)
__device__ __forceinline__ void pick4(const float* s, int q,
                                      float& r0, float& r1, float& r2, float& r3) {
    if (q == 0)      { r0 = s[0];  r1 = s[1];  r2 = s[2];  r3 = s[3];  }
    else if (q == 1) { r0 = s[4];  r1 = s[5];  r2 = s[6];  r3 = s[7];  }
    else if (q == 2) { r0 = s[8];  r1 = s[9];  r2 = s[10]; r3 = s[11]; }
    else             { r0 = s[12]; r1 = s[13]; r2 = s[14]; r3 = s[15]; }
}

// ---------------- group precompute: 4 threads per group, d-split ----------------
// thread q owns d in [24q, 24q+24) of the 96-dim concat [me0|me1|me2]:
// loads only its 6 float4 chunks (no redundant gathers), computes partial s[16],
// shuffle-reduces across the 4-lane cluster, packs its own me chunk to bf16.
__global__ __launch_bounds__(256) void grp_pre(
    const int* __restrict__ gm, const float* __restrict__ ue,
    const float* __restrict__ w1, const float* __restrict__ b1,
    uint32_t* __restrict__ grec, int NG)
{
    int tid = blockIdx.x * 256 + threadIdx.x;
    int g = tid >> 2, q = tid & 3;
    if (g >= NG) return;
    uint32_t* rec = grec + (size_t)g * GRECW;

    int u0 = gm[3 * g + 0], u1 = gm[3 * g + 1], u2 = gm[3 * g + 2];

    // load this thread's 24 embedding floats (6 x float4)
    float x[24];
    #pragma unroll
    for (int c = 0; c < 6; ++c) {
        int c4 = 6 * q + c;        // float4 index 0..23 over the 96-dim concat
        int m  = c4 >> 3;          // member 0..2
        int s4 = c4 & 7;           // float4 within the 32-float row
        int uu = (m == 0) ? u0 : ((m == 1) ? u1 : u2);
        float4 v = reinterpret_cast<const float4*>(ue + (size_t)uu * DD)[s4];
        x[4*c+0] = v.x; x[4*c+1] = v.y; x[4*c+2] = v.z; x[4*c+3] = v.w;
    }

    // partial s[16] over this thread's 24 d's (chain depth 24)
    float s[16];
    #pragma unroll
    for (int j = 0; j < 16; ++j) s[j] = 0.0f;
    #pragma unroll
    for (int k = 0; k < 24; ++k) {
        int d = 24 * q + k;
        const float4* wr = reinterpret_cast<const float4*>(w1 + d * 16);
        float4 w0 = wr[0], w1v = wr[1], w2v = wr[2], w3v = wr[3];
        float xv = x[k];
        s[0]  = fmaf(xv, w0.x,  s[0]);  s[1]  = fmaf(xv, w0.y,  s[1]);
        s[2]  = fmaf(xv, w0.z,  s[2]);  s[3]  = fmaf(xv, w0.w,  s[3]);
        s[4]  = fmaf(xv, w1v.x, s[4]);  s[5]  = fmaf(xv, w1v.y, s[5]);
        s[6]  = fmaf(xv, w1v.z, s[6]);  s[7]  = fmaf(xv, w1v.w, s[7]);
        s[8]  = fmaf(xv, w2v.x, s[8]);  s[9]  = fmaf(xv, w2v.y, s[9]);
        s[10] = fmaf(xv, w2v.z, s[10]); s[11] = fmaf(xv, w2v.w, s[11]);
        s[12] = fmaf(xv, w3v.x, s[12]); s[13] = fmaf(xv, w3v.y, s[13]);
        s[14] = fmaf(xv, w3v.z, s[14]); s[15] = fmaf(xv, w3v.w, s[15]);
    }
    // reduce across the 4-lane cluster (lanes 4-aligned: xor 1 then 2)
    #pragma unroll
    for (int j = 0; j < 16; ++j) {
        s[j] += __shfl_xor(s[j], 1, 64);
        s[j] += __shfl_xor(s[j], 2, 64);
    }

    // lane q stores s words [2q, 2q+1] (+b1)
    float r0, r1, r2, r3;
    pick4(s, q, r0, r1, r2, r3);
    const float* bp = b1 + 4 * q;
    uint2 sw;
    sw.x = pack2(r0 + bp[0], r1 + bp[1]);
    sw.y = pack2(r2 + bp[2], r3 + bp[3]);
    *reinterpret_cast<uint2*>(rec + 2 * q) = sw;

    // pack own me chunk: 24 floats -> 12 words at rec + 8 + 12q (16B-aligned)
    uint32_t* dst = rec + 8 + 12 * q;
    #pragma unroll
    for (int c = 0; c < 3; ++c) {
        uint4 o;
        o.x = pack2(x[8*c+0], x[8*c+1]);
        o.y = pack2(x[8*c+2], x[8*c+3]);
        o.z = pack2(x[8*c+4], x[8*c+5]);
        o.w = pack2(x[8*c+6], x[8*c+7]);
        *reinterpret_cast<uint4*>(dst + 4 * c) = o;
    }
}

// ---------------- item precompute: 4 threads per item, d-split ----------------
__global__ __launch_bounds__(256) void item_pre(
    const float* __restrict__ itemb, const float* __restrict__ w1,
    uint32_t* __restrict__ irec, int NI)
{
    int tid = blockIdx.x * 256 + threadIdx.x;
    int i = tid >> 2, q = tid & 3;
    if (i >= NI) return;
    uint32_t* rec = irec + (size_t)i * IRECW;

    // this thread's 8 ie floats (d in [8q, 8q+8))
    float x[8];
    {
        const float4* p = reinterpret_cast<const float4*>(itemb + (size_t)i * DD) + 2 * q;
        float4 v0 = p[0], v1 = p[1];
        x[0] = v0.x; x[1] = v0.y; x[2] = v0.z; x[3] = v0.w;
        x[4] = v1.x; x[5] = v1.y; x[6] = v1.z; x[7] = v1.w;
    }

    float t[16];
    #pragma unroll
    for (int j = 0; j < 16; ++j) t[j] = 0.0f;
    #pragma unroll
    for (int k = 0; k < 8; ++k) {
        int d = 8 * q + k;
        const float4* wr = reinterpret_cast<const float4*>(w1 + (96 + d) * 16);
        float4 w0 = wr[0], w1v = wr[1], w2v = wr[2], w3v = wr[3];
        float xv = x[k];
        t[0]  = fmaf(xv, w0.x,  t[0]);  t[1]  = fmaf(xv, w0.y,  t[1]);
        t[2]  = fmaf(xv, w0.z,  t[2]);  t[3]  = fmaf(xv, w0.w,  t[3]);
        t[4]  = fmaf(xv, w1v.x, t[4]);  t[5]  = fmaf(xv, w1v.y, t[5]);
        t[6]  = fmaf(xv, w1v.z, t[6]);  t[7]  = fmaf(xv, w1v.w, t[7]);
        t[8]  = fmaf(xv, w2v.x, t[8]);  t[9]  = fmaf(xv, w2v.y, t[9]);
        t[10] = fmaf(xv, w2v.z, t[10]); t[11] = fmaf(xv, w2v.w, t[11]);
        t[12] = fmaf(xv, w3v.x, t[12]); t[13] = fmaf(xv, w3v.y, t[13]);
        t[14] = fmaf(xv, w3v.z, t[14]); t[15] = fmaf(xv, w3v.w, t[15]);
    }
    #pragma unroll
    for (int j = 0; j < 16; ++j) {
        t[j] += __shfl_xor(t[j], 1, 64);
        t[j] += __shfl_xor(t[j], 2, 64);
    }

    float r0, r1, r2, r3;
    pick4(t, q, r0, r1, r2, r3);
    uint2 tw;
    tw.x = pack2(r0, r1);
    tw.y = pack2(r2, r3);
    *reinterpret_cast<uint2*>(rec + 2 * q) = tw;

    // pack own ie chunk: 8 floats -> 4 words at rec + 8 + 4q (16B-aligned)
    uint4 o;
    o.x = pack2(x[0], x[1]);
    o.y = pack2(x[2], x[3]);
    o.z = pack2(x[4], x[5]);
    o.w = pack2(x[6], x[7]);
    *reinterpret_cast<uint4*>(rec + 8 + 4 * q) = o;
}

// ---------------- per-element compute from record registers ----------------
__device__ __forceinline__ float agree_eval(
    const uint4* G, const uint4* I,
    const float* __restrict__ w2, const float* __restrict__ b2,
    const float* __restrict__ pw1, const float* __restrict__ pb1,
    const float* __restrict__ pw2, const float* __restrict__ pb2)
{
    // h = relu(s + t)
    float h[16];
    #pragma unroll
    for (int c = 0; c < 2; ++c) {
        uint4 sa = G[c];
        uint4 ta = I[c];
        h[8*c+0] = fmaxf(BLO(sa.x) + BLO(ta.x), 0.0f);
        h[8*c+1] = fmaxf(BHI(sa.x) + BHI(ta.x), 0.0f);
        h[8*c+2] = fmaxf(BLO(sa.y) + BLO(ta.y), 0.0f);
        h[8*c+3] = fmaxf(BHI(sa.y) + BHI(ta.y), 0.0f);
        h[8*c+4] = fmaxf(BLO(sa.z) + BLO(ta.z), 0.0f);
        h[8*c+5] = fmaxf(BHI(sa.z) + BHI(ta.z), 0.0f);
        h[8*c+6] = fmaxf(BLO(sa.w) + BLO(ta.w), 0.0f);
        h[8*c+7] = fmaxf(BHI(sa.w) + BHI(ta.w), 0.0f);
    }

    float l0 = b2[0], l1 = b2[1], l2 = b2[2];
    #pragma unroll
    for (int j = 0; j < 16; ++j) {
        l0 = fmaf(h[j], w2[j * 3 + 0], l0);
        l1 = fmaf(h[j], w2[j * 3 + 1], l1);
        l2 = fmaf(h[j], w2[j * 3 + 2], l2);
    }
    float mx = fmaxf(l0, fmaxf(l1, l2));
    float e0 = __expf(l0 - mx);
    float e1 = __expf(l1 - mx);
    float e2 = __expf(l2 - mx);
    float inv = 1.0f / (e0 + e1 + e2);
    float wt0 = e0 * inv, wt1 = e1 * inv, wt2 = e2 * inv;

    float g[32];
    #pragma unroll
    for (int c = 0; c < 4; ++c) {
        uint4 a  = G[2 + c];
        uint4 bq = G[6 + c];
        uint4 cq = G[10 + c];
        g[8*c+0] = fmaf(wt0, BLO(a.x), fmaf(wt1, BLO(bq.x), wt2 * BLO(cq.x)));
        g[8*c+1] = fmaf(wt0, BHI(a.x), fmaf(wt1, BHI(bq.x), wt2 * BHI(cq.x)));
        g[8*c+2] = fmaf(wt0, BLO(a.y), fmaf(wt1, BLO(bq.y), wt2 * BLO(cq.y)));
        g[8*c+3] = fmaf(wt0, BHI(a.y), fmaf(wt1, BHI(bq.y), wt2 * BHI(cq.y)));
        g[8*c+4] = fmaf(wt0, BLO(a.z), fmaf(wt1, BLO(bq.z), wt2 * BLO(cq.z)));
        g[8*c+5] = fmaf(wt0, BHI(a.z), fmaf(wt1, BHI(bq.z), wt2 * BHI(cq.z)));
        g[8*c+6] = fmaf(wt0, BLO(a.w), fmaf(wt1, BLO(bq.w), wt2 * BLO(cq.w)));
        g[8*c+7] = fmaf(wt0, BHI(a.w), fmaf(wt1, BHI(bq.w), wt2 * BHI(cq.w)));
    }

    float h2[8];
    #pragma unroll
    for (int j = 0; j < 8; ++j) h2[j] = pb1[j];

    #pragma unroll
    for (int c = 0; c < 4; ++c) {
        uint4 e4 = I[2 + c];
        float ef[8];
        ef[0] = BLO(e4.x); ef[1] = BHI(e4.x);
        ef[2] = BLO(e4.y); ef[3] = BHI(e4.y);
        ef[4] = BLO(e4.z); ef[5] = BHI(e4.z);
        ef[6] = BLO(e4.w); ef[7] = BHI(e4.w);
        #pragma unroll
        for (int r = 0; r < 8; ++r) {
            int d = 8 * c + r;
            float e  = ef[r];
            float gd = g[d];
            float ge = gd * e;
            #pragma unroll
            for (int j = 0; j < 8; ++j) {
                h2[j] = fmaf(ge, pw1[d * 8 + j],        h2[j]);
                h2[j] = fmaf(gd, pw1[(32 + d) * 8 + j], h2[j]);
                h2[j] = fmaf(e,  pw1[(64 + d) * 8 + j], h2[j]);
            }
        }
    }

    float z = pb2[0];
    #pragma unroll
    for (int j = 0; j < 8; ++j)
        z = fmaf(fmaxf(h2[j], 0.0f), pw2[j], z);

    return 1.0f / (1.0f + __expf(-z));
}

// ---------------- main: 2 batch elements per thread ----------------
// Element 0's ~490-FMA compute phase hides element 1's 20 record loads.
__global__ __launch_bounds__(256) void agree_main(
    const int* __restrict__ gi, const int* __restrict__ ii,
    const uint32_t* __restrict__ grec, const uint32_t* __restrict__ irec,
    const float* __restrict__ w2, const float* __restrict__ b2,
    const float* __restrict__ pw1, const float* __restrict__ pb1,
    const float* __restrict__ pw2, const float* __restrict__ pb2,
    float* __restrict__ out, int B)
{
    int t = blockIdx.x * 256 + threadIdx.x;
    int half = (B + 1) >> 1;
    if (t >= half) return;
    int b0 = t;
    int b1i = t + half;
    bool has1 = (b1i < B);

    const uint4* gr0 = reinterpret_cast<const uint4*>(grec + (size_t)gi[b0] * GRECW);
    const uint4* ir0 = reinterpret_cast<const uint4*>(irec + (size_t)ii[b0] * IRECW);
    int g1 = gi[has1 ? b1i : b0];
    int i1 = ii[has1 ? b1i : b0];
    const uint4* gr1 = reinterpret_cast<const uint4*>(grec + (size_t)g1 * GRECW);
    const uint4* ir1 = reinterpret_cast<const uint4*>(irec + (size_t)i1 * IRECW);

    uint4 G0[14], I0[6];
    #pragma unroll
    for (int c = 0; c < 14; ++c) G0[c] = gr0[c];
    #pragma unroll
    for (int c = 0; c < 6; ++c)  I0[c] = ir0[c];
    uint4 G1[14], I1[6];
    #pragma unroll
    for (int c = 0; c < 14; ++c) G1[c] = gr1[c];
    #pragma unroll
    for (int c = 0; c < 6; ++c)  I1[c] = ir1[c];

    out[b0] = agree_eval(G0, I0, w2, b2, pw1, pb1, pw2, pb2);
    float y1 = agree_eval(G1, I1, w2, b2, pw1, pb1, pw2, pb2);
    if (has1) out[b1i] = y1;
}

// ---------------- fallback (round-1 kernel) if ws too small ----------------
__global__ __launch_bounds__(256) void agree_fwd(
    const int* __restrict__ gi, const int* __restrict__ ii,
    const int* __restrict__ gm,
    const float* __restrict__ ue, const float* __restrict__ itemb,
    const float* __restrict__ w1, const float* __restrict__ b1,
    const float* __restrict__ w2, const float* __restrict__ b2,
    const float* __restrict__ pw1, const float* __restrict__ pb1,
    const float* __restrict__ pw2, const float* __restrict__ pb2,
    float* __restrict__ out, int B)
{
    int b = blockIdx.x * blockDim.x + threadIdx.x;
    if (b >= B) return;
    int g = gi[b], it = ii[b];
    int m0 = gm[3*g+0], m1 = gm[3*g+1], m2 = gm[3*g+2];
    float me[3][DD], iev[DD];
    {
        const float4* p0 = reinterpret_cast<const float4*>(ue + (size_t)m0 * DD);
        const float4* p1 = reinterpret_cast<const float4*>(ue + (size_t)m1 * DD);
        const float4* p2 = reinterpret_cast<const float4*>(ue + (size_t)m2 * DD);
        const float4* p3 = reinterpret_cast<const float4*>(itemb + (size_t)it * DD);
        #pragma unroll
        for (int c = 0; c < 8; ++c) {
            float4 v0 = p0[c], v1 = p1[c], v2 = p2[c], v3 = p3[c];
            me[0][4*c]=v0.x; me[0][4*c+1]=v0.y; me[0][4*c+2]=v0.z; me[0][4*c+3]=v0.w;
            me[1][4*c]=v1.x; me[1][4*c+1]=v1.y; me[1][4*c+2]=v1.z; me[1][4*c+3]=v1.w;
            me[2][4*c]=v2.x; me[2][4*c+1]=v2.y; me[2][4*c+2]=v2.z; me[2][4*c+3]=v2.w;
            iev[4*c]=v3.x; iev[4*c+1]=v3.y; iev[4*c+2]=v3.z; iev[4*c+3]=v3.w;
        }
    }
    float h[16];
    #pragma unroll
    for (int j = 0; j < 16; ++j) h[j] = b1[j];
    #pragma unroll
    for (int m = 0; m < 3; ++m)
        #pragma unroll
        for (int kk = 0; kk < DD; ++kk) {
            float xk = me[m][kk];
            #pragma unroll
            for (int j = 0; j < 16; ++j)
                h[j] = fmaf(xk, w1[(m*DD+kk)*16+j], h[j]);
        }
    #pragma unroll
    for (int kk = 0; kk < DD; ++kk) {
        float xk = iev[kk];
        #pragma unroll
        for (int j = 0; j < 16; ++j)
            h[j] = fmaf(xk, w1[(3*DD+kk)*16+j], h[j]);
    }
    #pragma unroll
    for (int j = 0; j < 16; ++j) h[j] = fmaxf(h[j], 0.0f);
    float l0 = b2[0], l1 = b2[1], l2 = b2[2];
    #pragma unroll
    for (int j = 0; j < 16; ++j) {
        l0 = fmaf(h[j], w2[j*3+0], l0);
        l1 = fmaf(h[j], w2[j*3+1], l1);
        l2 = fmaf(h[j], w2[j*3+2], l2);
    }
    float mx = fmaxf(l0, fmaxf(l1, l2));
    float e0 = __expf(l0-mx), e1 = __expf(l1-mx), e2 = __expf(l2-mx);
    float inv = 1.0f / (e0+e1+e2);
    float wt0 = e0*inv, wt1 = e1*inv, wt2 = e2*inv;
    float h2[8];
    #pragma unroll
    for (int j = 0; j < 8; ++j) h2[j] = pb1[j];
    #pragma unroll
    for (int d = 0; d < DD; ++d) {
        float gd  = wt0*me[0][d] + wt1*me[1][d] + wt2*me[2][d];
        float gie = gd * iev[d];
        #pragma unroll
        for (int j = 0; j < 8; ++j) {
            h2[j] = fmaf(gie,    pw1[d*8+j],          h2[j]);
            h2[j] = fmaf(gd,     pw1[(DD+d)*8+j],     h2[j]);
            h2[j] = fmaf(iev[d], pw1[(2*DD+d)*8+j],   h2[j]);
        }
    }
    float z = pb2[0];
    #pragma unroll
    for (int j = 0; j < 8; ++j)
        z = fmaf(fmaxf(h2[j], 0.0f), pw2[j], z);
    out[b] = 1.0f / (1.0f + __expf(-z));
}

extern "C" void kernel_launch(void* const* d_in, const int* in_sizes, int n_in,
                              void* d_out, int out_size, void* d_ws, size_t ws_size,
                              hipStream_t stream) {
    const int*   gi    = (const int*)d_in[0];
    const int*   ii    = (const int*)d_in[1];
    const int*   gm    = (const int*)d_in[2];
    const float* ue    = (const float*)d_in[3];
    const float* itemb = (const float*)d_in[4];
    const float* w1    = (const float*)d_in[5];
    const float* b1    = (const float*)d_in[6];
    const float* w2    = (const float*)d_in[7];
    const float* b2    = (const float*)d_in[8];
    const float* pw1   = (const float*)d_in[9];
    const float* pb1   = (const float*)d_in[10];
    const float* pw2   = (const float*)d_in[11];
    const float* pb2   = (const float*)d_in[12];
    float* out = (float*)d_out;

    int B  = in_sizes[0];
    int NG = in_sizes[2] / 3;
    int NI = in_sizes[4] / DD;

    size_t need = ((size_t)NG * GRECW + (size_t)NI * IRECW) * sizeof(uint32_t) + 512;
    if (ws_size >= need) {
        char* ws = (char*)d_ws;
        uint32_t* grec = (uint32_t*)ws;
        uint32_t* irec = grec + (((size_t)NG * GRECW + 63) & ~(size_t)63);

        hipLaunchKernelGGL(grp_pre, dim3((4 * NG + 255) / 256), dim3(256), 0, stream,
                           gm, ue, w1, b1, grec, NG);
        hipLaunchKernelGGL(item_pre, dim3((4 * NI + 255) / 256), dim3(256), 0, stream,
                           itemb, w1, irec, NI);
        int half = (B + 1) >> 1;
        hipLaunchKernelGGL(agree_main, dim3((half + 255) / 256), dim3(256), 0, stream,
                           gi, ii, grec, irec, w2, b2, pw1, pb1, pw2, pb2, out, B);
    } else {
        hipLaunchKernelGGL(agree_fwd, dim3((B + 255) / 256), dim3(256), 0, stream,
                           gi, ii, gm, ue, itemb, w1, b1, w2, b2,
                           pw1, pb1, pw2, pb2, out, B);
    }
}

// Round 6
// 230.054 us; speedup vs baseline: 1.2058x; 1.2058x over previous
//
#include <hip/hip_runtime.h>
#include <math.h>
#include <stdint.h>

#define DD 32
// group record: stride 48 words (192B, 3 cache lines):
//   words[0..7]  s[16]  bf16  (b1 baked in)
//   words[8..19] P[3][8] bf16 (P[m][j] = me_m . pw1_B, exact B-term)
//   words[20..43] me[96] fp8 e4m3 (concat me0|me1|me2)
// item record: stride 16 words (64B, 1 cache line):
//   words[0..3]  t[16]  fp8
//   words[4..7]  Q[8]   bf16 (Q[j] = ie . pw1_C, exact C-term)
//   words[8..15] ie[32] fp8
#define GRECW 48
#define IRECW 16

// ---------------- bf16 helpers ----------------
__device__ __forceinline__ uint32_t bf16rne(float f) {
    uint32_t u = __float_as_uint(f);
    return (u + 0x7fffu + ((u >> 16) & 1u)) >> 16;
}
__device__ __forceinline__ uint32_t pack2(float a, float b) {
    return bf16rne(a) | (bf16rne(b) << 16);
}
#define BLO(u) __uint_as_float((u) << 16)
#define BHI(u) __uint_as_float((u) & 0xffff0000u)

// ---------------- fp8 e4m3 helpers ----------------
__device__ inline uint32_t sw_enc(float f) {
    float af = fabsf(f);
    uint32_t s = (__float_as_uint(f) >> 24) & 0x80u;
    if (!(af >= 0.015625f)) {                 // denormal / zero
        int m = (int)rintf(af * 512.0f);
        if (m > 7) return s | 0x08u;
        return s | (uint32_t)m;
    }
    if (af >= 448.0f) return s | 0x7eu;
    int e; float fr = frexpf(af, &e);         // af = fr*2^e, fr in [0.5,1)
    int M = (int)rintf(fr * 16.0f) - 8;       // RNE 3-bit mantissa
    int E = e + 6;
    if (M == 8) { M = 0; E += 1; }
    return s | ((uint32_t)E << 3) | (uint32_t)M;
}
__device__ inline float sw_dec(uint32_t b) {
    uint32_t em = b & 0x7fu;
    float v = (em < 8) ? (float)em * (1.0f / 512.0f)
                       : ldexpf((float)(8 + (em & 7)), (int)(em >> 3) - 10);
    return (b & 0x80u) ? -v : v;
}

typedef float f32x2 __attribute__((ext_vector_type(2)));

__device__ __forceinline__ uint32_t enc4(float a, float b, float c, float d) {
#if __has_builtin(__builtin_amdgcn_cvt_pk_fp8_f32)
    int v = 0;
    v = __builtin_amdgcn_cvt_pk_fp8_f32(a, b, v, false);
    v = __builtin_amdgcn_cvt_pk_fp8_f32(c, d, v, true);
    return (uint32_t)v;
#else
    return sw_enc(a) | (sw_enc(b) << 8) | (sw_enc(c) << 16) | (sw_enc(d) << 24);
#endif
}
__device__ __forceinline__ void dec4(uint32_t w, float& o0, float& o1, float& o2, float& o3) {
#if __has_builtin(__builtin_amdgcn_cvt_pk_f32_fp8)
    f32x2 lo = __builtin_amdgcn_cvt_pk_f32_fp8((int)w, false);
    f32x2 hi = __builtin_amdgcn_cvt_pk_f32_fp8((int)w, true);
    o0 = lo.x; o1 = lo.y; o2 = hi.x; o3 = hi.y;
#else
    o0 = sw_dec(w & 255u); o1 = sw_dec((w >> 8) & 255u);
    o2 = sw_dec((w >> 16) & 255u); o3 = sw_dec(w >> 24);
#endif
}

// ---------------- merged precompute: groups then items ----------------
// 4 threads per entity; thread q owns dims [8q,8q+8) of each 32-dim row.
__global__ __launch_bounds__(256) void pre_all(
    const int* __restrict__ gm, const float* __restrict__ ue,
    const float* __restrict__ itemb,
    const float* __restrict__ w1, const float* __restrict__ b1,
    const float* __restrict__ pw1,
    uint32_t* __restrict__ grec, uint32_t* __restrict__ irec,
    int NG, int NI, int GBLK)
{
    if ((int)blockIdx.x < GBLK) {
        int tid = blockIdx.x * 256 + threadIdx.x;
        int g = tid >> 2, q = tid & 3;
        if (g >= NG) return;
        uint32_t* rec = grec + (size_t)g * GRECW;
        int u0 = gm[3 * g + 0], u1 = gm[3 * g + 1], u2 = gm[3 * g + 2];

        float x0[8], x1[8], x2[8];
        {
            const float4* p = reinterpret_cast<const float4*>(ue + (size_t)u0 * DD) + 2 * q;
            float4 a = p[0], b = p[1];
            x0[0]=a.x; x0[1]=a.y; x0[2]=a.z; x0[3]=a.w; x0[4]=b.x; x0[5]=b.y; x0[6]=b.z; x0[7]=b.w;
        }
        {
            const float4* p = reinterpret_cast<const float4*>(ue + (size_t)u1 * DD) + 2 * q;
            float4 a = p[0], b = p[1];
            x1[0]=a.x; x1[1]=a.y; x1[2]=a.z; x1[3]=a.w; x1[4]=b.x; x1[5]=b.y; x1[6]=b.z; x1[7]=b.w;
        }
        {
            const float4* p = reinterpret_cast<const float4*>(ue + (size_t)u2 * DD) + 2 * q;
            float4 a = p[0], b = p[1];
            x2[0]=a.x; x2[1]=a.y; x2[2]=a.z; x2[3]=a.w; x2[4]=b.x; x2[5]=b.y; x2[6]=b.z; x2[7]=b.w;
        }

        float s[16]; float P0[8], P1[8], P2[8];
        #pragma unroll
        for (int j = 0; j < 16; ++j) s[j] = 0.0f;
        #pragma unroll
        for (int j = 0; j < 8; ++j) { P0[j] = 0.0f; P1[j] = 0.0f; P2[j] = 0.0f; }

        #pragma unroll
        for (int k = 0; k < 8; ++k) {
            int dm = 8 * q + k;
            const float4* br = reinterpret_cast<const float4*>(pw1 + (DD + dm) * 8);
            float4 B0 = br[0], B1 = br[1];
            // member 0
            {
                const float4* wr = reinterpret_cast<const float4*>(w1 + (0 * DD + dm) * 16);
                float4 wa = wr[0], wb = wr[1], wc = wr[2], wd = wr[3];
                float xv = x0[k];
                s[0]=fmaf(xv,wa.x,s[0]); s[1]=fmaf(xv,wa.y,s[1]); s[2]=fmaf(xv,wa.z,s[2]); s[3]=fmaf(xv,wa.w,s[3]);
                s[4]=fmaf(xv,wb.x,s[4]); s[5]=fmaf(xv,wb.y,s[5]); s[6]=fmaf(xv,wb.z,s[6]); s[7]=fmaf(xv,wb.w,s[7]);
                s[8]=fmaf(xv,wc.x,s[8]); s[9]=fmaf(xv,wc.y,s[9]); s[10]=fmaf(xv,wc.z,s[10]); s[11]=fmaf(xv,wc.w,s[11]);
                s[12]=fmaf(xv,wd.x,s[12]); s[13]=fmaf(xv,wd.y,s[13]); s[14]=fmaf(xv,wd.z,s[14]); s[15]=fmaf(xv,wd.w,s[15]);
                P0[0]=fmaf(xv,B0.x,P0[0]); P0[1]=fmaf(xv,B0.y,P0[1]); P0[2]=fmaf(xv,B0.z,P0[2]); P0[3]=fmaf(xv,B0.w,P0[3]);
                P0[4]=fmaf(xv,B1.x,P0[4]); P0[5]=fmaf(xv,B1.y,P0[5]); P0[6]=fmaf(xv,B1.z,P0[6]); P0[7]=fmaf(xv,B1.w,P0[7]);
            }
            // member 1
            {
                const float4* wr = reinterpret_cast<const float4*>(w1 + (1 * DD + dm) * 16);
                float4 wa = wr[0], wb = wr[1], wc = wr[2], wd = wr[3];
                float xv = x1[k];
                s[0]=fmaf(xv,wa.x,s[0]); s[1]=fmaf(xv,wa.y,s[1]); s[2]=fmaf(xv,wa.z,s[2]); s[3]=fmaf(xv,wa.w,s[3]);
                s[4]=fmaf(xv,wb.x,s[4]); s[5]=fmaf(xv,wb.y,s[5]); s[6]=fmaf(xv,wb.z,s[6]); s[7]=fmaf(xv,wb.w,s[7]);
                s[8]=fmaf(xv,wc.x,s[8]); s[9]=fmaf(xv,wc.y,s[9]); s[10]=fmaf(xv,wc.z,s[10]); s[11]=fmaf(xv,wc.w,s[11]);
                s[12]=fmaf(xv,wd.x,s[12]); s[13]=fmaf(xv,wd.y,s[13]); s[14]=fmaf(xv,wd.z,s[14]); s[15]=fmaf(xv,wd.w,s[15]);
                P1[0]=fmaf(xv,B0.x,P1[0]); P1[1]=fmaf(xv,B0.y,P1[1]); P1[2]=fmaf(xv,B0.z,P1[2]); P1[3]=fmaf(xv,B0.w,P1[3]);
                P1[4]=fmaf(xv,B1.x,P1[4]); P1[5]=fmaf(xv,B1.y,P1[5]); P1[6]=fmaf(xv,B1.z,P1[6]); P1[7]=fmaf(xv,B1.w,P1[7]);
            }
            // member 2
            {
                const float4* wr = reinterpret_cast<const float4*>(w1 + (2 * DD + dm) * 16);
                float4 wa = wr[0], wb = wr[1], wc = wr[2], wd = wr[3];
                float xv = x2[k];
                s[0]=fmaf(xv,wa.x,s[0]); s[1]=fmaf(xv,wa.y,s[1]); s[2]=fmaf(xv,wa.z,s[2]); s[3]=fmaf(xv,wa.w,s[3]);
                s[4]=fmaf(xv,wb.x,s[4]); s[5]=fmaf(xv,wb.y,s[5]); s[6]=fmaf(xv,wb.z,s[6]); s[7]=fmaf(xv,wb.w,s[7]);
                s[8]=fmaf(xv,wc.x,s[8]); s[9]=fmaf(xv,wc.y,s[9]); s[10]=fmaf(xv,wc.z,s[10]); s[11]=fmaf(xv,wc.w,s[11]);
                s[12]=fmaf(xv,wd.x,s[12]); s[13]=fmaf(xv,wd.y,s[13]); s[14]=fmaf(xv,wd.z,s[14]); s[15]=fmaf(xv,wd.w,s[15]);
                P2[0]=fmaf(xv,B0.x,P2[0]); P2[1]=fmaf(xv,B0.y,P2[1]); P2[2]=fmaf(xv,B0.z,P2[2]); P2[3]=fmaf(xv,B0.w,P2[3]);
                P2[4]=fmaf(xv,B1.x,P2[4]); P2[5]=fmaf(xv,B1.y,P2[5]); P2[6]=fmaf(xv,B1.z,P2[6]); P2[7]=fmaf(xv,B1.w,P2[7]);
            }
        }

        #pragma unroll
        for (int j = 0; j < 16; ++j) {
            s[j] += __shfl_xor(s[j], 1, 64);
            s[j] += __shfl_xor(s[j], 2, 64);
        }
        #pragma unroll
        for (int j = 0; j < 8; ++j) {
            P0[j] += __shfl_xor(P0[j], 1, 64); P0[j] += __shfl_xor(P0[j], 2, 64);
            P1[j] += __shfl_xor(P1[j], 1, 64); P1[j] += __shfl_xor(P1[j], 2, 64);
            P2[j] += __shfl_xor(P2[j], 1, 64); P2[j] += __shfl_xor(P2[j], 2, 64);
        }

        if (q == 0) {
            uint4 o;
            o.x = pack2(s[0] + b1[0],  s[1] + b1[1]);
            o.y = pack2(s[2] + b1[2],  s[3] + b1[3]);
            o.z = pack2(s[4] + b1[4],  s[5] + b1[5]);
            o.w = pack2(s[6] + b1[6],  s[7] + b1[7]);
            *reinterpret_cast<uint4*>(rec + 0) = o;
            uint4 o2;
            o2.x = pack2(s[8] + b1[8],   s[9] + b1[9]);
            o2.y = pack2(s[10] + b1[10], s[11] + b1[11]);
            o2.z = pack2(s[12] + b1[12], s[13] + b1[13]);
            o2.w = pack2(s[14] + b1[14], s[15] + b1[15]);
            *reinterpret_cast<uint4*>(rec + 4) = o2;
        } else if (q == 1) {
            uint4 o;
            o.x = pack2(P0[0], P0[1]); o.y = pack2(P0[2], P0[3]);
            o.z = pack2(P0[4], P0[5]); o.w = pack2(P0[6], P0[7]);
            *reinterpret_cast<uint4*>(rec + 8) = o;
            uint4 o2;
            o2.x = pack2(P1[0], P1[1]); o2.y = pack2(P1[2], P1[3]);
            o2.z = pack2(P1[4], P1[5]); o2.w = pack2(P1[6], P1[7]);
            *reinterpret_cast<uint4*>(rec + 12) = o2;
        } else if (q == 2) {
            uint4 o;
            o.x = pack2(P2[0], P2[1]); o.y = pack2(P2[2], P2[3]);
            o.z = pack2(P2[4], P2[5]); o.w = pack2(P2[6], P2[7]);
            *reinterpret_cast<uint4*>(rec + 16) = o;
        }
        uint2 w;
        w.x = enc4(x0[0], x0[1], x0[2], x0[3]);
        w.y = enc4(x0[4], x0[5], x0[6], x0[7]);
        *reinterpret_cast<uint2*>(rec + 20 + 2 * q) = w;
        w.x = enc4(x1[0], x1[1], x1[2], x1[3]);
        w.y = enc4(x1[4], x1[5], x1[6], x1[7]);
        *reinterpret_cast<uint2*>(rec + 28 + 2 * q) = w;
        w.x = enc4(x2[0], x2[1], x2[2], x2[3]);
        w.y = enc4(x2[4], x2[5], x2[6], x2[7]);
        *reinterpret_cast<uint2*>(rec + 36 + 2 * q) = w;
    } else {
        int tid = (blockIdx.x - GBLK) * 256 + threadIdx.x;
        int i = tid >> 2, q = tid & 3;
        if (i >= NI) return;
        uint32_t* rec = irec + (size_t)i * IRECW;

        float y[8];
        {
            const float4* p = reinterpret_cast<const float4*>(itemb + (size_t)i * DD) + 2 * q;
            float4 a = p[0], b = p[1];
            y[0]=a.x; y[1]=a.y; y[2]=a.z; y[3]=a.w; y[4]=b.x; y[5]=b.y; y[6]=b.z; y[7]=b.w;
        }
        float t[16], Q[8];
        #pragma unroll
        for (int j = 0; j < 16; ++j) t[j] = 0.0f;
        #pragma unroll
        for (int j = 0; j < 8; ++j) Q[j] = 0.0f;

        #pragma unroll
        for (int k = 0; k < 8; ++k) {
            int dm = 8 * q + k;
            const float4* wr = reinterpret_cast<const float4*>(w1 + (96 + dm) * 16);
            float4 wa = wr[0], wb = wr[1], wc = wr[2], wd = wr[3];
            const float4* cr = reinterpret_cast<const float4*>(pw1 + (2 * DD + dm) * 8);
            float4 C0 = cr[0], C1 = cr[1];
            float xv = y[k];
            t[0]=fmaf(xv,wa.x,t[0]); t[1]=fmaf(xv,wa.y,t[1]); t[2]=fmaf(xv,wa.z,t[2]); t[3]=fmaf(xv,wa.w,t[3]);
            t[4]=fmaf(xv,wb.x,t[4]); t[5]=fmaf(xv,wb.y,t[5]); t[6]=fmaf(xv,wb.z,t[6]); t[7]=fmaf(xv,wb.w,t[7]);
            t[8]=fmaf(xv,wc.x,t[8]); t[9]=fmaf(xv,wc.y,t[9]); t[10]=fmaf(xv,wc.z,t[10]); t[11]=fmaf(xv,wc.w,t[11]);
            t[12]=fmaf(xv,wd.x,t[12]); t[13]=fmaf(xv,wd.y,t[13]); t[14]=fmaf(xv,wd.z,t[14]); t[15]=fmaf(xv,wd.w,t[15]);
            Q[0]=fmaf(xv,C0.x,Q[0]); Q[1]=fmaf(xv,C0.y,Q[1]); Q[2]=fmaf(xv,C0.z,Q[2]); Q[3]=fmaf(xv,C0.w,Q[3]);
            Q[4]=fmaf(xv,C1.x,Q[4]); Q[5]=fmaf(xv,C1.y,Q[5]); Q[6]=fmaf(xv,C1.z,Q[6]); Q[7]=fmaf(xv,C1.w,Q[7]);
        }
        #pragma unroll
        for (int j = 0; j < 16; ++j) {
            t[j] += __shfl_xor(t[j], 1, 64);
            t[j] += __shfl_xor(t[j], 2, 64);
        }
        #pragma unroll
        for (int j = 0; j < 8; ++j) {
            Q[j] += __shfl_xor(Q[j], 1, 64);
            Q[j] += __shfl_xor(Q[j], 2, 64);
        }

        if (q == 0) {
            uint4 o;
            o.x = enc4(t[0], t[1], t[2], t[3]);
            o.y = enc4(t[4], t[5], t[6], t[7]);
            o.z = enc4(t[8], t[9], t[10], t[11]);
            o.w = enc4(t[12], t[13], t[14], t[15]);
            *reinterpret_cast<uint4*>(rec + 0) = o;
        } else if (q == 1) {
            uint4 o;
            o.x = pack2(Q[0], Q[1]); o.y = pack2(Q[2], Q[3]);
            o.z = pack2(Q[4], Q[5]); o.w = pack2(Q[6], Q[7]);
            *reinterpret_cast<uint4*>(rec + 4) = o;
        }
        uint2 w;
        w.x = enc4(y[0], y[1], y[2], y[3]);
        w.y = enc4(y[4], y[5], y[6], y[7]);
        *reinterpret_cast<uint2*>(rec + 8 + 2 * q) = w;
    }
}

// ---------------- main: 1 thread per batch element ----------------
__global__ __launch_bounds__(256) void agree_main(
    const int* __restrict__ gi, const int* __restrict__ ii,
    const uint32_t* __restrict__ grec, const uint32_t* __restrict__ irec,
    const float* __restrict__ w2, const float* __restrict__ b2,
    const float* __restrict__ pw1, const float* __restrict__ pb1,
    const float* __restrict__ pw2, const float* __restrict__ pb2,
    float* __restrict__ out, int B)
{
    int b = blockIdx.x * 256 + threadIdx.x;
    if (b >= B) return;

    const uint4* gr4 = reinterpret_cast<const uint4*>(grec + (size_t)gi[b] * GRECW);
    const uint4* ir4 = reinterpret_cast<const uint4*>(irec + (size_t)ii[b] * IRECW);

    uint4 G0 = gr4[0], G1 = gr4[1], G2 = gr4[2], G3 = gr4[3], G4 = gr4[4];
    uint4 G5 = gr4[5], G6 = gr4[6], G7 = gr4[7], G8 = gr4[8], G9 = gr4[9], G10 = gr4[10];
    uint4 I0 = ir4[0], I1 = ir4[1], I2 = ir4[2], I3 = ir4[3];
    __builtin_amdgcn_sched_barrier(0);

    // ---- phase A: h = relu(s + t), logits, softmax ----
    float tt[16];
    dec4(I0.x, tt[0], tt[1], tt[2], tt[3]);
    dec4(I0.y, tt[4], tt[5], tt[6], tt[7]);
    dec4(I0.z, tt[8], tt[9], tt[10], tt[11]);
    dec4(I0.w, tt[12], tt[13], tt[14], tt[15]);
    float h[16];
    h[0]  = fmaxf(BLO(G0.x) + tt[0],  0.0f);
    h[1]  = fmaxf(BHI(G0.x) + tt[1],  0.0f);
    h[2]  = fmaxf(BLO(G0.y) + tt[2],  0.0f);
    h[3]  = fmaxf(BHI(G0.y) + tt[3],  0.0f);
    h[4]  = fmaxf(BLO(G0.z) + tt[4],  0.0f);
    h[5]  = fmaxf(BHI(G0.z) + tt[5],  0.0f);
    h[6]  = fmaxf(BLO(G0.w) + tt[6],  0.0f);
    h[7]  = fmaxf(BHI(G0.w) + tt[7],  0.0f);
    h[8]  = fmaxf(BLO(G1.x) + tt[8],  0.0f);
    h[9]  = fmaxf(BHI(G1.x) + tt[9],  0.0f);
    h[10] = fmaxf(BLO(G1.y) + tt[10], 0.0f);
    h[11] = fmaxf(BHI(G1.y) + tt[11], 0.0f);
    h[12] = fmaxf(BLO(G1.z) + tt[12], 0.0f);
    h[13] = fmaxf(BHI(G1.z) + tt[13], 0.0f);
    h[14] = fmaxf(BLO(G1.w) + tt[14], 0.0f);
    h[15] = fmaxf(BHI(G1.w) + tt[15], 0.0f);

    float l0 = b2[0], l1 = b2[1], l2 = b2[2];
    #pragma unroll
    for (int j = 0; j < 16; ++j) {
        l0 = fmaf(h[j], w2[j * 3 + 0], l0);
        l1 = fmaf(h[j], w2[j * 3 + 1], l1);
        l2 = fmaf(h[j], w2[j * 3 + 2], l2);
    }
    float mx = fmaxf(l0, fmaxf(l1, l2));
    float e0 = __expf(l0 - mx);
    float e1 = __expf(l1 - mx);
    float e2 = __expf(l2 - mx);
    float inv = 1.0f / (e0 + e1 + e2);
    float wt0 = e0 * inv, wt1 = e1 * inv, wt2 = e2 * inv;

    // ---- phase B: h2 = pb1 + Q + sum_m wt_m P[m] ----
    float h2[8];
    h2[0] = pb1[0] + BLO(I1.x); h2[1] = pb1[1] + BHI(I1.x);
    h2[2] = pb1[2] + BLO(I1.y); h2[3] = pb1[3] + BHI(I1.y);
    h2[4] = pb1[4] + BLO(I1.z); h2[5] = pb1[5] + BHI(I1.z);
    h2[6] = pb1[6] + BLO(I1.w); h2[7] = pb1[7] + BHI(I1.w);
    {
        float p0[8], p1[8], p2[8];
        p0[0]=BLO(G2.x); p0[1]=BHI(G2.x); p0[2]=BLO(G2.y); p0[3]=BHI(G2.y);
        p0[4]=BLO(G2.z); p0[5]=BHI(G2.z); p0[6]=BLO(G2.w); p0[7]=BHI(G2.w);
        p1[0]=BLO(G3.x); p1[1]=BHI(G3.x); p1[2]=BLO(G3.y); p1[3]=BHI(G3.y);
        p1[4]=BLO(G3.z); p1[5]=BHI(G3.z); p1[6]=BLO(G3.w); p1[7]=BHI(G3.w);
        p2[0]=BLO(G4.x); p2[1]=BHI(G4.x); p2[2]=BLO(G4.y); p2[3]=BHI(G4.y);
        p2[4]=BLO(G4.z); p2[5]=BHI(G4.z); p2[6]=BLO(G4.w); p2[7]=BHI(G4.w);
        #pragma unroll
        for (int j = 0; j < 8; ++j)
            h2[j] = fmaf(wt0, p0[j], fmaf(wt1, p1[j], fmaf(wt2, p2[j], h2[j])));
    }

    // ---- phase C: h2 += (g .* ie) @ A, 8-dim chunks, all-static indexing ----
#define DO_CHUNK(DBASE, w00, w01, w10, w11, w20, w21, we0, we1)                 \
    {                                                                           \
        float m0[8], m1[8], m2[8], ee[8];                                       \
        dec4(w00, m0[0], m0[1], m0[2], m0[3]);                                  \
        dec4(w01, m0[4], m0[5], m0[6], m0[7]);                                  \
        dec4(w10, m1[0], m1[1], m1[2], m1[3]);                                  \
        dec4(w11, m1[4], m1[5], m1[6], m1[7]);                                  \
        dec4(w20, m2[0], m2[1], m2[2], m2[3]);                                  \
        dec4(w21, m2[4], m2[5], m2[6], m2[7]);                                  \
        dec4(we0, ee[0], ee[1], ee[2], ee[3]);                                  \
        dec4(we1, ee[4], ee[5], ee[6], ee[7]);                                  \
        _Pragma("unroll")                                                       \
        for (int r = 0; r < 8; ++r) {                                           \
            float gd = fmaf(wt0, m0[r], fmaf(wt1, m1[r], wt2 * m2[r]));         \
            float ge = gd * ee[r];                                              \
            const float* arow = pw1 + (DBASE + r) * 8;                          \
            _Pragma("unroll")                                                   \
            for (int j = 0; j < 8; ++j) h2[j] = fmaf(ge, arow[j], h2[j]);       \
        }                                                                       \
    }

    DO_CHUNK(0,  G5.x, G5.y, G7.x, G7.y, G9.x,  G9.y,  I2.x, I2.y)
    DO_CHUNK(8,  G5.z, G5.w, G7.z, G7.w, G9.z,  G9.w,  I2.z, I2.w)
    DO_CHUNK(16, G6.x, G6.y, G8.x, G8.y, G10.x, G10.y, I3.x, I3.y)
    DO_CHUNK(24, G6.z, G6.w, G8.z, G8.w, G10.z, G10.w, I3.z, I3.w)
#undef DO_CHUNK

    float z = pb2[0];
    #pragma unroll
    for (int j = 0; j < 8; ++j)
        z = fmaf(fmaxf(h2[j], 0.0f), pw2[j], z);

    out[b] = 1.0f / (1.0f + __expf(-z));
}

// ---------------- fallback (round-1 kernel) if ws too small ----------------
__global__ __launch_bounds__(256) void agree_fwd(
    const int* __restrict__ gi, const int* __restrict__ ii,
    const int* __restrict__ gm,
    const float* __restrict__ ue, const float* __restrict__ itemb,
    const float* __restrict__ w1, const float* __restrict__ b1,
    const float* __restrict__ w2, const float* __restrict__ b2,
    const float* __restrict__ pw1, const float* __restrict__ pb1,
    const float* __restrict__ pw2, const float* __restrict__ pb2,
    float* __restrict__ out, int B)
{
    int b = blockIdx.x * blockDim.x + threadIdx.x;
    if (b >= B) return;
    int g = gi[b], it = ii[b];
    int m0 = gm[3*g+0], m1 = gm[3*g+1], m2 = gm[3*g+2];
    float me[3][DD], iev[DD];
    {
        const float4* p0 = reinterpret_cast<const float4*>(ue + (size_t)m0 * DD);
        const float4* p1 = reinterpret_cast<const float4*>(ue + (size_t)m1 * DD);
        const float4* p2 = reinterpret_cast<const float4*>(ue + (size_t)m2 * DD);
        const float4* p3 = reinterpret_cast<const float4*>(itemb + (size_t)it * DD);
        #pragma unroll
        for (int c = 0; c < 8; ++c) {
            float4 v0 = p0[c], v1 = p1[c], v2 = p2[c], v3 = p3[c];
            me[0][4*c]=v0.x; me[0][4*c+1]=v0.y; me[0][4*c+2]=v0.z; me[0][4*c+3]=v0.w;
            me[1][4*c]=v1.x; me[1][4*c+1]=v1.y; me[1][4*c+2]=v1.z; me[1][4*c+3]=v1.w;
            me[2][4*c]=v2.x; me[2][4*c+1]=v2.y; me[2][4*c+2]=v2.z; me[2][4*c+3]=v2.w;
            iev[4*c]=v3.x; iev[4*c+1]=v3.y; iev[4*c+2]=v3.z; iev[4*c+3]=v3.w;
        }
    }
    float h[16];
    #pragma unroll
    for (int j = 0; j < 16; ++j) h[j] = b1[j];
    #pragma unroll
    for (int m = 0; m < 3; ++m)
        #pragma unroll
        for (int kk = 0; kk < DD; ++kk) {
            float xk = me[m][kk];
            #pragma unroll
            for (int j = 0; j < 16; ++j)
                h[j] = fmaf(xk, w1[(m*DD+kk)*16+j], h[j]);
        }
    #pragma unroll
    for (int kk = 0; kk < DD; ++kk) {
        float xk = iev[kk];
        #pragma unroll
        for (int j = 0; j < 16; ++j)
            h[j] = fmaf(xk, w1[(3*DD+kk)*16+j], h[j]);
    }
    #pragma unroll
    for (int j = 0; j < 16; ++j) h[j] = fmaxf(h[j], 0.0f);
    float l0 = b2[0], l1 = b2[1], l2 = b2[2];
    #pragma unroll
    for (int j = 0; j < 16; ++j) {
        l0 = fmaf(h[j], w2[j*3+0], l0);
        l1 = fmaf(h[j], w2[j*3+1], l1);
        l2 = fmaf(h[j], w2[j*3+2], l2);
    }
    float mx = fmaxf(l0, fmaxf(l1, l2));
    float e0 = __expf(l0-mx), e1 = __expf(l1-mx), e2 = __expf(l2-mx);
    float inv = 1.0f / (e0+e1+e2);
    float wt0 = e0*inv, wt1 = e1*inv, wt2 = e2*inv;
    float h2[8];
    #pragma unroll
    for (int j = 0; j < 8; ++j) h2[j] = pb1[j];
    #pragma unroll
    for (int d = 0; d < DD; ++d) {
        float gd  = wt0*me[0][d] + wt1*me[1][d] + wt2*me[2][d];
        float gie = gd * iev[d];
        #pragma unroll
        for (int j = 0; j < 8; ++j) {
            h2[j] = fmaf(gie,    pw1[d*8+j],          h2[j]);
            h2[j] = fmaf(gd,     pw1[(DD+d)*8+j],     h2[j]);
            h2[j] = fmaf(iev[d], pw1[(2*DD+d)*8+j],   h2[j]);
        }
    }
    float z = pb2[0];
    #pragma unroll
    for (int j = 0; j < 8; ++j)
        z = fmaf(fmaxf(h2[j], 0.0f), pw2[j], z);
    out[b] = 1.0f / (1.0f + __expf(-z));
}

extern "C" void kernel_launch(void* const* d_in, const int* in_sizes, int n_in,
                              void* d_out, int out_size, void* d_ws, size_t ws_size,
                              hipStream_t stream) {
    const int*   gi    = (const int*)d_in[0];
    const int*   ii    = (const int*)d_in[1];
    const int*   gm    = (const int*)d_in[2];
    const float* ue    = (const float*)d_in[3];
    const float* itemb = (const float*)d_in[4];
    const float* w1    = (const float*)d_in[5];
    const float* b1    = (const float*)d_in[6];
    const float* w2    = (const float*)d_in[7];
    const float* b2    = (const float*)d_in[8];
    const float* pw1   = (const float*)d_in[9];
    const float* pb1   = (const float*)d_in[10];
    const float* pw2   = (const float*)d_in[11];
    const float* pb2   = (const float*)d_in[12];
    float* out = (float*)d_out;

    int B  = in_sizes[0];
    int NG = in_sizes[2] / 3;
    int NI = in_sizes[4] / DD;

    size_t gbytes = ((size_t)NG * GRECW * 4 + 255) & ~(size_t)255;
    size_t ibytes = (size_t)NI * IRECW * 4;
    size_t need = gbytes + ibytes + 256;
    if (ws_size >= need) {
        char* ws = (char*)d_ws;
        uint32_t* grec = (uint32_t*)ws;
        uint32_t* irec = (uint32_t*)(ws + gbytes);

        int GBLK = (4 * NG + 255) / 256;
        int IBLK = (4 * NI + 255) / 256;
        hipLaunchKernelGGL(pre_all, dim3(GBLK + IBLK), dim3(256), 0, stream,
                           gm, ue, itemb, w1, b1, pw1, grec, irec, NG, NI, GBLK);
        hipLaunchKernelGGL(agree_main, dim3((B + 255) / 256), dim3(256), 0, stream,
                           gi, ii, grec, irec, w2, b2, pw1, pb1, pw2, pb2, out, B);
    } else {
        hipLaunchKernelGGL(agree_fwd, dim3((B + 255) / 256), dim3(256), 0, stream,
                           gi, ii, gm, ue, itemb, w1, b1, w2, b2,
                           pw1, pb1, pw2, pb2, out, B);
    }
}